// Round 16
// baseline (90.701 us; speedup 1.0000x reference)
//
#include <hip/hip_runtime.h>

typedef unsigned short ushort_t;
typedef __attribute__((ext_vector_type(8))) short bf16x8;
typedef __attribute__((ext_vector_type(4))) float f32x4;

#define BS 2
#define NS 48
#define NO 48
#define RD 512
#define MD 256
#define M1 (BS*NS*NO)   // 4608 (b,s,o1) rows
#define LN_EPS 1e-6f

// RNE
__device__ __forceinline__ short f2bf(float f) {
    union { float f; unsigned u; } v; v.f = f;
    unsigned u = v.u;
    return (short)((u + 0x7fffu + ((u >> 16) & 1u)) >> 16);
}
// fast round-to-nearest (ties away): 2 VALU ops
__device__ __forceinline__ short f2bf_fast(float f) {
    union { float f; unsigned u; } v; v.f = f;
    return (short)((v.u + 0x8000u) >> 16);
}

// ---------------------------------------------------------------------------
// prep: pack W (K x N, f32 row-major) into MFMA fragment layout, bf16:
//   dst[((ntG*NKS + ksG)*64 + lane)*8 + e] = W[ksG*32 + (lane>>4)*8 + e][ntG*16 + (lane&15)]
// Serves both A and B operand roles of mfma_16x16x32 (identical lane maps).
// Blocks: 0-31 W1, 32-63 W2, 64-79 We. 512 threads.
// ---------------------------------------------------------------------------
__global__ __launch_bounds__(512) void prep_kernel(
    const float* __restrict__ W1, const float* __restrict__ W2,
    const float* __restrict__ We,
    ushort_t* __restrict__ w1F, ushort_t* __restrict__ w2F,
    ushort_t* __restrict__ weF)
{
    __shared__ float tile[64][65];
    int b = blockIdx.x;
    const float* src; ushort_t* dst; int NKS, kT, nT;
    if (b < 32)      { src = W1; dst = w1F; NKS = 16; kT = b >> 2;        nT = b & 3; }
    else if (b < 64) { src = W2; dst = w2F; NKS = 16; kT = (b - 32) >> 2; nT = b & 3; }
    else             { src = We; dst = weF; NKS = 8;  kT = (b - 64) >> 2; nT = b & 3; }
    int R0 = kT * 64, C0 = nT * 64;
    int tid = threadIdx.x;
#pragma unroll
    for (int pass = 0; pass < 2; ++pass) {
        int kl = pass * 32 + (tid >> 4);
        int nl = (tid & 15) * 4;
        float4 v = *reinterpret_cast<const float4*>(src + (size_t)(R0 + kl) * MD + C0 + nl);
        tile[kl][nl + 0] = v.x; tile[kl][nl + 1] = v.y;
        tile[kl][nl + 2] = v.z; tile[kl][nl + 3] = v.w;
    }
    __syncthreads();
    int f = tid >> 6, lane = tid & 63, lr = lane & 15, lg = lane >> 4;
    int ntl = f >> 1, ksl = f & 1;
    int ntG = (C0 >> 4) + ntl, ksG = (R0 >> 5) + ksl;
    bf16x8 v;
#pragma unroll
    for (int e = 0; e < 8; ++e)
        v[e] = f2bf(tile[ksl * 32 + lg * 8 + e][ntl * 16 + lr]);
    *reinterpret_cast<bf16x8*>(dst + ((size_t)(ntG * NKS + ksG) * 64 + lane) * 8) = v;
}

// ---------------------------------------------------------------------------
// stage1: P1 = rel @ W1 + b1, P2 = rel @ W2 + b2  (bf16 MFMA, fp32 out)
// 576 blocks: mt = b>>1, which = b&1. 256 threads = 4 waves, wave = 64 cols.
// ---------------------------------------------------------------------------
__global__ __launch_bounds__(256) void stage1_kernel(
    const float* __restrict__ rel,
    const ushort_t* __restrict__ w1F, const ushort_t* __restrict__ w2F,
    const float* __restrict__ b1, const float* __restrict__ b2,
    float* __restrict__ p1, float* __restrict__ p2)
{
    __shared__ __align__(16) char ldsA[16 * RD * 2];   // 16 KB
    int blk = blockIdx.x;
    int mt = blk >> 1, which = blk & 1;
    const ushort_t* wF = which ? w2F : w1F;
    const float* bias  = which ? b2 : b1;
    float* out         = which ? p2 : p1;
    int tid = threadIdx.x, wid = tid >> 6, lane = tid & 63;
    int lr = lane & 15, lg = lane >> 4;

#pragma unroll
    for (int it = 0; it < 8; ++it) {
        int rr = it * 2 + (tid >> 7);
        int c  = (tid & 127) * 4;
        float4 v = *reinterpret_cast<const float4*>(rel + (size_t)(mt * 16 + rr) * RD + c);
        short4 s;
        s.x = f2bf_fast(v.x); s.y = f2bf_fast(v.y);
        s.z = f2bf_fast(v.z); s.w = f2bf_fast(v.w);
        *reinterpret_cast<short4*>(ldsA + rr * (RD * 2) + ((c * 2) ^ ((rr & 7) << 4))) = s;
    }
    __syncthreads();

    int n0 = wid * 64;
    f32x4 acc[4] = {};
#pragma unroll
    for (int ks = 0; ks < 16; ++ks) {
        bf16x8 a = *reinterpret_cast<const bf16x8*>(
            ldsA + lr * (RD * 2) + ((ks * 64 + lg * 16) ^ ((lr & 7) << 4)));
#pragma unroll
        for (int nt = 0; nt < 4; ++nt) {
            int ntG = (n0 >> 4) + nt;
            bf16x8 bfr = *reinterpret_cast<const bf16x8*>(
                wF + ((size_t)(ntG * 16 + ks) * 64 + lane) * 8);
            acc[nt] = __builtin_amdgcn_mfma_f32_16x16x32_bf16(a, bfr, acc[nt], 0, 0, 0);
        }
    }
#pragma unroll
    for (int nt = 0; nt < 4; ++nt) {
        int col = n0 + nt * 16 + lr;
        float bv = bias[col];
#pragma unroll
        for (int r = 0; r < 4; ++r) {
            int orow = mt * 16 + lg * 4 + r;
            out[(size_t)orow * MD + col] = acc[nt][r] + bv;
        }
    }
}

// ---------------------------------------------------------------------------
// stage2 (R11 math, 1024-thread layout): one block per (b,s,o1), transposed
// GEMM h^T = We^T * prod^T. 16 waves; wave owns 16 n-rows (one 16-tile).
// Per-wave state: afrag 8x4 VGPR held as two 4-ks batches (16 live), acc 12
// -> peak ~55-60 VGPR; __launch_bounds__(1024,8) caps at 64 -> 8 waves/SIMD
// -> 2 blocks/CU x 16 waves = 32 waves/CU (2x R11) for store-duty/TLP.
// All LDS patterns identical to R11 (verified) with wid in [0,16).
// ---------------------------------------------------------------------------
__global__ __launch_bounds__(1024, 8) void stage2_kernel(
    const float* __restrict__ p1, const float* __restrict__ p2,
    const ushort_t* __restrict__ weF,
    const float* __restrict__ be, const float* __restrict__ gamma,
    const float* __restrict__ beta, float* __restrict__ out)
{
    __shared__ __align__(16) char lds[49152];   // prod tile (24.5K) / epilogue (48K)
    __shared__ float pS1[NO][16];
    __shared__ float pS2[NO][16];
    __shared__ float muS[NO];
    __shared__ float rsS[NO];

    int d    = blockIdx.x;
    int bid  = (d & 7) * 576 + (d >> 3);   // 4608 = 8*576, bijective
    int grp  = (bid / NO) * NO;
    int tid  = threadIdx.x;
    int wid  = tid >> 6;              // 0..15
    int lane = tid & 63;
    int lr   = lane & 15;
    int lg   = lane >> 4;
    int m0w  = wid * 16;              // wave's n-row base (one 16-tile)

    // ---- stage prod rows into LDS: 48 rows, 3 per wave ----
    const float* p1r = p1 + (size_t)bid * MD;
#pragma unroll
    for (int i = 0; i < 3; ++i) {
        int r  = i * 16 + wid;        // 0..47
        int m0 = lane * 4;
        float4 x = *reinterpret_cast<const float4*>(p1r + m0);
        float4 y = *reinterpret_cast<const float4*>(p2 + (size_t)(grp + r) * MD + m0);
        short4 s;
        s.x = f2bf_fast(x.x * y.x); s.y = f2bf_fast(x.y * y.y);
        s.z = f2bf_fast(x.z * y.z); s.w = f2bf_fast(x.w * y.w);
        *reinterpret_cast<short4*>(lds + r * (MD * 2) + ((m0 * 2) ^ ((r & 7) << 4))) = s;
    }

    // ---- afrag batch A (ks 0-3): wave's n-tile index = wid ----
    bf16x8 af[4];
#pragma unroll
    for (int ks = 0; ks < 4; ++ks)
        af[ks] = *reinterpret_cast<const bf16x8*>(
            weF + ((size_t)(wid * 8 + ks) * 64 + lane) * 8);
    __syncthreads();

    // ---- K-pass A (ks 0-3) ----
    f32x4 acc[3] = {};
#pragma unroll
    for (int ks = 0; ks < 4; ++ks) {
        bf16x8 b[3];
#pragma unroll
        for (int nt = 0; nt < 3; ++nt) {
            int r = nt * 16 + lr;
            b[nt] = *reinterpret_cast<const bf16x8*>(
                lds + r * (MD * 2) + ((ks * 64 + lg * 16) ^ ((r & 7) << 4)));
        }
#pragma unroll
        for (int nt = 0; nt < 3; ++nt)
            acc[nt] = __builtin_amdgcn_mfma_f32_16x16x32_bf16(
                af[ks], b[nt], acc[nt], 0, 0, 0);
    }

    // ---- afrag batch B (ks 4-7), then K-pass B ----
#pragma unroll
    for (int ks = 0; ks < 4; ++ks)
        af[ks] = *reinterpret_cast<const bf16x8*>(
            weF + ((size_t)(wid * 8 + ks + 4) * 64 + lane) * 8);
#pragma unroll
    for (int ks = 0; ks < 4; ++ks) {
        bf16x8 b[3];
#pragma unroll
        for (int nt = 0; nt < 3; ++nt) {
            int r = nt * 16 + lr;
            b[nt] = *reinterpret_cast<const bf16x8*>(
                lds + r * (MD * 2) + (((ks + 4) * 64 + lg * 16) ^ ((r & 7) << 4)));
        }
#pragma unroll
        for (int nt = 0; nt < 3; ++nt)
            acc[nt] = __builtin_amdgcn_mfma_f32_16x16x32_bf16(
                af[ks], b[nt], acc[nt], 0, 0, 0);
    }

    // ---- add be (per-n) ----
    {
        float4 bev = *reinterpret_cast<const float4*>(be + m0w + lg * 4);
#pragma unroll
        for (int nt = 0; nt < 3; ++nt) {
            acc[nt][0] += bev.x; acc[nt][1] += bev.y;
            acc[nt][2] += bev.z; acc[nt][3] += bev.w;
        }
    }

    // ---- LN partials: per col r, lane-local 4-sum + xor16 + xor32 ----
#pragma unroll
    for (int nt = 0; nt < 3; ++nt) {
        float s1 = 0.f, s2 = 0.f;
#pragma unroll
        for (int r = 0; r < 4; ++r) {
            float v = acc[nt][r];
            s1 += v; s2 += v * v;
        }
        s1 += __shfl_xor(s1, 16); s2 += __shfl_xor(s2, 16);
        s1 += __shfl_xor(s1, 32); s2 += __shfl_xor(s2, 32);
        if (lane < 16) {
            pS1[nt * 16 + lane][wid] = s1;
            pS2[nt * 16 + lane][wid] = s2;
        }
    }
    __syncthreads();   // pS ready; also fences last K-loop lds reads

    // ---- finalize stats: one thread per col ----
    if (tid < NO) {
        float S1 = 0.f, S2 = 0.f;
#pragma unroll
        for (int w = 0; w < 4; ++w) {
            f32x4 a = *reinterpret_cast<const f32x4*>(&pS1[tid][w * 4]);
            f32x4 c = *reinterpret_cast<const f32x4*>(&pS2[tid][w * 4]);
            S1 += a[0] + a[1] + a[2] + a[3];
            S2 += c[0] + c[1] + c[2] + c[3];
        }
        float m  = S1 * (1.0f / MD);
        float var = S2 * (1.0f / MD) - m * m;
        muS[tid] = m;
        rsS[tid] = rsqrtf(var + LN_EPS);
    }
    __syncthreads();

    // ---- epilogue: LN apply -> stage all 3 chunks (48KB) -> ONE barrier ->
    //      one contiguous 48KB store burst (wave-contiguous 1KB per instr).
    float4 g4 = *reinterpret_cast<const float4*>(gamma + m0w + lg * 4);
    float4 b4 = *reinterpret_cast<const float4*>(beta  + m0w + lg * 4);
#pragma unroll
    for (int nt = 0; nt < 3; ++nt) {
        int r = nt * 16 + lr;
        float mu = muS[r];
        float rs = rsS[r];
        float4 o;
        o.x = (acc[nt][0] - mu) * rs * g4.x + b4.x;
        o.y = (acc[nt][1] - mu) * rs * g4.y + b4.y;
        o.z = (acc[nt][2] - mu) * rs * g4.z + b4.z;
        o.w = (acc[nt][3] - mu) * rs * g4.w + b4.w;
        int n4 = (m0w + lg * 4) * 4;           // byte offset of n in row
        *reinterpret_cast<float4*>(
            lds + nt * 16384 + lr * 1024 + (n4 ^ ((lr & 7) << 4))) = o;
    }
    __syncthreads();   // all 48 rows staged

    size_t ob = (size_t)bid * NO * MD;
#pragma unroll
    for (int nt = 0; nt < 3; ++nt) {
        int rl = wid;                 // 16 rows per chunk, 1 per wave
        float4 o = *reinterpret_cast<const float4*>(
            lds + nt * 16384 + rl * 1024 + ((lane * 16) ^ ((rl & 7) << 4)));
        *reinterpret_cast<float4*>(
            out + ob + (size_t)(nt * 16 + rl) * MD + lane * 4) = o;
    }
}

// ---------------------------------------------------------------------------
extern "C" void kernel_launch(void* const* d_in, const int* in_sizes, int n_in,
                              void* d_out, int out_size, void* d_ws, size_t ws_size,
                              hipStream_t stream) {
    const float* rel   = (const float*)d_in[0];
    const float* W1    = (const float*)d_in[1];
    const float* b1    = (const float*)d_in[2];
    const float* W2    = (const float*)d_in[3];
    const float* b2    = (const float*)d_in[4];
    const float* We    = (const float*)d_in[5];
    const float* be    = (const float*)d_in[6];
    const float* gamma = (const float*)d_in[7];
    const float* beta  = (const float*)d_in[8];
    float* out = (float*)d_out;

    char* ws = (char*)d_ws;
    // ws layout (bytes): w1F 512K | w2F 512K | weF 128K | p1 4.5M | p2 4.5M
    ushort_t* w1F = (ushort_t*)(ws);
    ushort_t* w2F = (ushort_t*)(ws + 524288);
    ushort_t* weF = (ushort_t*)(ws + 1048576);
    float*    p1  = (float*)   (ws + 1179648);
    float*    p2  = (float*)   (ws + 1179648 + 4718592);

    prep_kernel<<<80, 512, 0, stream>>>(W1, W2, We, w1F, w2F, weF);
    stage1_kernel<<<576, 256, 0, stream>>>(rel, w1F, w2F, b1, b2, p1, p2);
    stage2_kernel<<<M1, 1024, 0, stream>>>(p1, p2, weF, be, gamma, beta, out);
}

// Round 17
// 82.991 us; speedup vs baseline: 1.0929x; 1.0929x over previous
//
#include <hip/hip_runtime.h>

typedef unsigned short ushort_t;
typedef __attribute__((ext_vector_type(8))) short bf16x8;
typedef __attribute__((ext_vector_type(4))) float f32x4;

#define BS 2
#define NS 48
#define NO 48
#define RD 512
#define MD 256
#define M1 (BS*NS*NO)   // 4608 (b,s,o1) rows
#define LN_EPS 1e-6f

// RNE
__device__ __forceinline__ short f2bf(float f) {
    union { float f; unsigned u; } v; v.f = f;
    unsigned u = v.u;
    return (short)((u + 0x7fffu + ((u >> 16) & 1u)) >> 16);
}
// fast round-to-nearest (ties away): 2 VALU ops
__device__ __forceinline__ short f2bf_fast(float f) {
    union { float f; unsigned u; } v; v.f = f;
    return (short)((v.u + 0x8000u) >> 16);
}

// ---------------------------------------------------------------------------
// prep: pack W (K x N, f32 row-major) into MFMA fragment layout, bf16:
//   dst[((ntG*NKS + ksG)*64 + lane)*8 + e] = W[ksG*32 + (lane>>4)*8 + e][ntG*16 + (lane&15)]
// Serves both A and B operand roles of mfma_16x16x32 (identical lane maps).
// Blocks: 0-31 W1, 32-63 W2, 64-79 We. 512 threads.
// ---------------------------------------------------------------------------
__global__ __launch_bounds__(512) void prep_kernel(
    const float* __restrict__ W1, const float* __restrict__ W2,
    const float* __restrict__ We,
    ushort_t* __restrict__ w1F, ushort_t* __restrict__ w2F,
    ushort_t* __restrict__ weF)
{
    __shared__ float tile[64][65];
    int b = blockIdx.x;
    const float* src; ushort_t* dst; int NKS, kT, nT;
    if (b < 32)      { src = W1; dst = w1F; NKS = 16; kT = b >> 2;        nT = b & 3; }
    else if (b < 64) { src = W2; dst = w2F; NKS = 16; kT = (b - 32) >> 2; nT = b & 3; }
    else             { src = We; dst = weF; NKS = 8;  kT = (b - 64) >> 2; nT = b & 3; }
    int R0 = kT * 64, C0 = nT * 64;
    int tid = threadIdx.x;
#pragma unroll
    for (int pass = 0; pass < 2; ++pass) {
        int kl = pass * 32 + (tid >> 4);
        int nl = (tid & 15) * 4;
        float4 v = *reinterpret_cast<const float4*>(src + (size_t)(R0 + kl) * MD + C0 + nl);
        tile[kl][nl + 0] = v.x; tile[kl][nl + 1] = v.y;
        tile[kl][nl + 2] = v.z; tile[kl][nl + 3] = v.w;
    }
    __syncthreads();
    int f = tid >> 6, lane = tid & 63, lr = lane & 15, lg = lane >> 4;
    int ntl = f >> 1, ksl = f & 1;
    int ntG = (C0 >> 4) + ntl, ksG = (R0 >> 5) + ksl;
    bf16x8 v;
#pragma unroll
    for (int e = 0; e < 8; ++e)
        v[e] = f2bf(tile[ksl * 32 + lg * 8 + e][ntl * 16 + lr]);
    *reinterpret_cast<bf16x8*>(dst + ((size_t)(ntG * NKS + ksG) * 64 + lane) * 8) = v;
}

// ---------------------------------------------------------------------------
// stage1: P1 = rel @ W1 + b1, P2 = rel @ W2 + b2  (bf16 MFMA, fp32 out)
// 576 blocks: mt = b>>1, which = b&1. 256 threads = 4 waves, wave = 64 cols.
// ---------------------------------------------------------------------------
__global__ __launch_bounds__(256) void stage1_kernel(
    const float* __restrict__ rel,
    const ushort_t* __restrict__ w1F, const ushort_t* __restrict__ w2F,
    const float* __restrict__ b1, const float* __restrict__ b2,
    float* __restrict__ p1, float* __restrict__ p2)
{
    __shared__ __align__(16) char ldsA[16 * RD * 2];   // 16 KB
    int blk = blockIdx.x;
    int mt = blk >> 1, which = blk & 1;
    const ushort_t* wF = which ? w2F : w1F;
    const float* bias  = which ? b2 : b1;
    float* out         = which ? p2 : p1;
    int tid = threadIdx.x, wid = tid >> 6, lane = tid & 63;
    int lr = lane & 15, lg = lane >> 4;

#pragma unroll
    for (int it = 0; it < 8; ++it) {
        int rr = it * 2 + (tid >> 7);
        int c  = (tid & 127) * 4;
        float4 v = *reinterpret_cast<const float4*>(rel + (size_t)(mt * 16 + rr) * RD + c);
        short4 s;
        s.x = f2bf_fast(v.x); s.y = f2bf_fast(v.y);
        s.z = f2bf_fast(v.z); s.w = f2bf_fast(v.w);
        *reinterpret_cast<short4*>(ldsA + rr * (RD * 2) + ((c * 2) ^ ((rr & 7) << 4))) = s;
    }
    __syncthreads();

    int n0 = wid * 64;
    f32x4 acc[4] = {};
#pragma unroll
    for (int ks = 0; ks < 16; ++ks) {
        bf16x8 a = *reinterpret_cast<const bf16x8*>(
            ldsA + lr * (RD * 2) + ((ks * 64 + lg * 16) ^ ((lr & 7) << 4)));
#pragma unroll
        for (int nt = 0; nt < 4; ++nt) {
            int ntG = (n0 >> 4) + nt;
            bf16x8 bfr = *reinterpret_cast<const bf16x8*>(
                wF + ((size_t)(ntG * 16 + ks) * 64 + lane) * 8);
            acc[nt] = __builtin_amdgcn_mfma_f32_16x16x32_bf16(a, bfr, acc[nt], 0, 0, 0);
        }
    }
#pragma unroll
    for (int nt = 0; nt < 4; ++nt) {
        int col = n0 + nt * 16 + lr;
        float bv = bias[col];
#pragma unroll
        for (int r = 0; r < 4; ++r) {
            int orow = mt * 16 + lg * 4 + r;
            out[(size_t)orow * MD + col] = acc[nt][r] + bv;
        }
    }
}

// ---------------------------------------------------------------------------
// stage2 (best measured configuration, = R11): one block per (b,s,o1),
// transposed GEMM h^T = We^T * prod^T. XCD swizzle for group L2 locality.
// Epilogue: LN apply -> ALL THREE 16-row chunks staged in a 48KB LDS buffer
// -> ONE barrier -> one uninterrupted 48KB burst of wave-contiguous 1KB
// stores (the fill-kernel pattern; worth +13us vs scattered stores).
// Staging loads issued before afrag loads (staging feeds the first barrier).
// ---------------------------------------------------------------------------
__global__ __launch_bounds__(512, 4) void stage2_kernel(
    const float* __restrict__ p1, const float* __restrict__ p2,
    const ushort_t* __restrict__ weF,
    const float* __restrict__ be, const float* __restrict__ gamma,
    const float* __restrict__ beta, float* __restrict__ out)
{
    __shared__ __align__(16) char lds[49152];   // prod tile (24.5K) / epilogue (48K)
    __shared__ float pS1[NO][8];
    __shared__ float pS2[NO][8];
    __shared__ float muS[NO];
    __shared__ float rsS[NO];

    int d    = blockIdx.x;
    int bid  = (d & 7) * 576 + (d >> 3);   // 4608 = 8*576, bijective
    int grp  = (bid / NO) * NO;
    int tid  = threadIdx.x;
    int wid  = tid >> 6;
    int lane = tid & 63;
    int lr   = lane & 15;
    int lg   = lane >> 4;
    int m0w  = wid * 32;              // wave's n-row base

    // ---- stage prod rows into LDS (coalesced 1KB reads, swizzled writes) ----
    const float* p1r = p1 + (size_t)bid * MD;
#pragma unroll
    for (int i = 0; i < 6; ++i) {
        int r  = i * 8 + wid;
        int m0 = lane * 4;
        float4 x = *reinterpret_cast<const float4*>(p1r + m0);
        float4 y = *reinterpret_cast<const float4*>(p2 + (size_t)(grp + r) * MD + m0);
        short4 s;
        s.x = f2bf_fast(x.x * y.x); s.y = f2bf_fast(x.y * y.y);
        s.z = f2bf_fast(x.z * y.z); s.w = f2bf_fast(x.w * y.w);
        *reinterpret_cast<short4*>(lds + r * (MD * 2) + ((m0 * 2) ^ ((r & 7) << 4))) = s;
    }

    // ---- A fragments (weF): 16 coalesced 1KB loads (needed after barrier) ----
    bf16x8 afrag[2][8];
#pragma unroll
    for (int mt = 0; mt < 2; ++mt) {
        int ntG = (m0w >> 4) + mt;
#pragma unroll
        for (int ks = 0; ks < 8; ++ks)
            afrag[mt][ks] = *reinterpret_cast<const bf16x8*>(
                weF + ((size_t)(ntG * 8 + ks) * 64 + lane) * 8);
    }
    __syncthreads();

    // ---- K-loop: A from regs, B from LDS ----
    f32x4 acc[2][3] = {};
#pragma unroll
    for (int ks = 0; ks < 8; ++ks) {
        bf16x8 b[3];
#pragma unroll
        for (int nt = 0; nt < 3; ++nt) {
            int r = nt * 16 + lr;
            b[nt] = *reinterpret_cast<const bf16x8*>(
                lds + r * (MD * 2) + ((ks * 64 + lg * 16) ^ ((r & 7) << 4)));
        }
#pragma unroll
        for (int mt = 0; mt < 2; ++mt)
#pragma unroll
            for (int nt = 0; nt < 3; ++nt)
                acc[mt][nt] = __builtin_amdgcn_mfma_f32_16x16x32_bf16(
                    afrag[mt][ks], b[nt], acc[mt][nt], 0, 0, 0);
    }

    // ---- add be (per-n = per output row of h^T) ----
#pragma unroll
    for (int mt = 0; mt < 2; ++mt) {
        float4 bev = *reinterpret_cast<const float4*>(be + m0w + mt * 16 + lg * 4);
#pragma unroll
        for (int nt = 0; nt < 3; ++nt) {
            acc[mt][nt][0] += bev.x; acc[mt][nt][1] += bev.y;
            acc[mt][nt][2] += bev.z; acc[mt][nt][3] += bev.w;
        }
    }

    // ---- LN partials: per col r, lane-local 8-sum + xor16 + xor32 ----
#pragma unroll
    for (int nt = 0; nt < 3; ++nt) {
        float s1 = 0.f, s2 = 0.f;
#pragma unroll
        for (int mt = 0; mt < 2; ++mt)
#pragma unroll
            for (int r = 0; r < 4; ++r) {
                float v = acc[mt][nt][r];
                s1 += v; s2 += v * v;
            }
        s1 += __shfl_xor(s1, 16); s2 += __shfl_xor(s2, 16);
        s1 += __shfl_xor(s1, 32); s2 += __shfl_xor(s2, 32);
        if (lane < 16) {
            pS1[nt * 16 + lane][wid] = s1;
            pS2[nt * 16 + lane][wid] = s2;
        }
    }
    __syncthreads();   // pS ready; also fences last K-loop lds reads

    // ---- finalize stats: one thread per col ----
    if (tid < NO) {
        f32x4 a0 = *reinterpret_cast<const f32x4*>(&pS1[tid][0]);
        f32x4 a1 = *reinterpret_cast<const f32x4*>(&pS1[tid][4]);
        f32x4 b0 = *reinterpret_cast<const f32x4*>(&pS2[tid][0]);
        f32x4 b1v = *reinterpret_cast<const f32x4*>(&pS2[tid][4]);
        float S1 = a0[0]+a0[1]+a0[2]+a0[3] + a1[0]+a1[1]+a1[2]+a1[3];
        float S2 = b0[0]+b0[1]+b0[2]+b0[3] + b1v[0]+b1v[1]+b1v[2]+b1v[3];
        float m  = S1 * (1.0f / MD);
        float var = S2 * (1.0f / MD) - m * m;
        muS[tid] = m;
        rsS[tid] = rsqrtf(var + LN_EPS);
    }
    __syncthreads();

    // ---- epilogue: LN apply -> stage all 3 chunks (48KB) -> ONE barrier ->
    //      one contiguous 48KB store burst (wave-contiguous 1KB per instr).
    float4 g4[2], b4[2];
#pragma unroll
    for (int mt = 0; mt < 2; ++mt) {
        g4[mt] = *reinterpret_cast<const float4*>(gamma + m0w + mt * 16 + lg * 4);
        b4[mt] = *reinterpret_cast<const float4*>(beta  + m0w + mt * 16 + lg * 4);
    }
#pragma unroll
    for (int nt = 0; nt < 3; ++nt) {
        int r = nt * 16 + lr;
        float mu = muS[r];
        float rs = rsS[r];
#pragma unroll
        for (int mt = 0; mt < 2; ++mt) {
            float4 o;
            o.x = (acc[mt][nt][0] - mu) * rs * g4[mt].x + b4[mt].x;
            o.y = (acc[mt][nt][1] - mu) * rs * g4[mt].y + b4[mt].y;
            o.z = (acc[mt][nt][2] - mu) * rs * g4[mt].z + b4[mt].z;
            o.w = (acc[mt][nt][3] - mu) * rs * g4[mt].w + b4[mt].w;
            int n4 = (m0w + mt * 16 + lg * 4) * 4;           // byte offset of n
            *reinterpret_cast<float4*>(
                lds + nt * 16384 + lr * 1024 + (n4 ^ ((lr & 7) << 4))) = o;
        }
    }
    __syncthreads();   // all 48 rows staged

    size_t ob = (size_t)bid * NO * MD;
#pragma unroll
    for (int nt = 0; nt < 3; ++nt) {
#pragma unroll
        for (int j = 0; j < 2; ++j) {
            int rl = wid * 2 + j;     // 16 rows per chunk, 2 per wave
            float4 o = *reinterpret_cast<const float4*>(
                lds + nt * 16384 + rl * 1024 + ((lane * 16) ^ ((rl & 7) << 4)));
            *reinterpret_cast<float4*>(
                out + ob + (size_t)(nt * 16 + rl) * MD + lane * 4) = o;
        }
    }
}

// ---------------------------------------------------------------------------
extern "C" void kernel_launch(void* const* d_in, const int* in_sizes, int n_in,
                              void* d_out, int out_size, void* d_ws, size_t ws_size,
                              hipStream_t stream) {
    const float* rel   = (const float*)d_in[0];
    const float* W1    = (const float*)d_in[1];
    const float* b1    = (const float*)d_in[2];
    const float* W2    = (const float*)d_in[3];
    const float* b2    = (const float*)d_in[4];
    const float* We    = (const float*)d_in[5];
    const float* be    = (const float*)d_in[6];
    const float* gamma = (const float*)d_in[7];
    const float* beta  = (const float*)d_in[8];
    float* out = (float*)d_out;

    char* ws = (char*)d_ws;
    // ws layout (bytes): w1F 512K | w2F 512K | weF 128K | p1 4.5M | p2 4.5M
    ushort_t* w1F = (ushort_t*)(ws);
    ushort_t* w2F = (ushort_t*)(ws + 524288);
    ushort_t* weF = (ushort_t*)(ws + 1048576);
    float*    p1  = (float*)   (ws + 1179648);
    float*    p2  = (float*)   (ws + 1179648 + 4718592);

    prep_kernel<<<80, 512, 0, stream>>>(W1, W2, We, w1F, w2F, weF);
    stage1_kernel<<<576, 256, 0, stream>>>(rel, w1F, w2F, b1, b2, p1, p2);
    stage2_kernel<<<M1, 512, 0, stream>>>(p1, p2, weF, be, gamma, beta, out);
}

// Round 19
// 82.584 us; speedup vs baseline: 1.0983x; 1.0049x over previous
//
#include <hip/hip_runtime.h>

typedef unsigned short ushort_t;
typedef __attribute__((ext_vector_type(8))) short bf16x8;
typedef __attribute__((ext_vector_type(4))) float f32x4;

#define BS 2
#define NS 48
#define NO 48
#define RD 512
#define MD 256
#define M1 (BS*NS*NO)   // 4608 (b,s,o1) rows
#define LN_EPS 1e-6f

// RNE
__device__ __forceinline__ short f2bf(float f) {
    union { float f; unsigned u; } v; v.f = f;
    unsigned u = v.u;
    return (short)((u + 0x7fffu + ((u >> 16) & 1u)) >> 16);
}
// fast round-to-nearest (ties away): 2 VALU ops
__device__ __forceinline__ short f2bf_fast(float f) {
    union { float f; unsigned u; } v; v.f = f;
    return (short)((v.u + 0x8000u) >> 16);
}

// ---------------------------------------------------------------------------
// prep: pack W (K x N, f32 row-major) into MFMA fragment layout, bf16:
//   dst[((ntG*NKS + ksG)*64 + lane)*8 + e] = W[ksG*32 + (lane>>4)*8 + e][ntG*16 + (lane&15)]
// Serves both A and B operand roles of mfma_16x16x32 (identical lane maps).
// Blocks: 0-31 W1, 32-63 W2, 64-79 We. 512 threads.
// ---------------------------------------------------------------------------
__global__ __launch_bounds__(512) void prep_kernel(
    const float* __restrict__ W1, const float* __restrict__ W2,
    const float* __restrict__ We,
    ushort_t* __restrict__ w1F, ushort_t* __restrict__ w2F,
    ushort_t* __restrict__ weF)
{
    __shared__ float tile[64][65];
    int b = blockIdx.x;
    const float* src; ushort_t* dst; int NKS, kT, nT;
    if (b < 32)      { src = W1; dst = w1F; NKS = 16; kT = b >> 2;        nT = b & 3; }
    else if (b < 64) { src = W2; dst = w2F; NKS = 16; kT = (b - 32) >> 2; nT = b & 3; }
    else             { src = We; dst = weF; NKS = 8;  kT = (b - 64) >> 2; nT = b & 3; }
    int R0 = kT * 64, C0 = nT * 64;
    int tid = threadIdx.x;
#pragma unroll
    for (int pass = 0; pass < 2; ++pass) {
        int kl = pass * 32 + (tid >> 4);
        int nl = (tid & 15) * 4;
        float4 v = *reinterpret_cast<const float4*>(src + (size_t)(R0 + kl) * MD + C0 + nl);
        tile[kl][nl + 0] = v.x; tile[kl][nl + 1] = v.y;
        tile[kl][nl + 2] = v.z; tile[kl][nl + 3] = v.w;
    }
    __syncthreads();
    int f = tid >> 6, lane = tid & 63, lr = lane & 15, lg = lane >> 4;
    int ntl = f >> 1, ksl = f & 1;
    int ntG = (C0 >> 4) + ntl, ksG = (R0 >> 5) + ksl;
    bf16x8 v;
#pragma unroll
    for (int e = 0; e < 8; ++e)
        v[e] = f2bf(tile[ksl * 32 + lg * 8 + e][ntl * 16 + lr]);
    *reinterpret_cast<bf16x8*>(dst + ((size_t)(ntG * NKS + ksG) * 64 + lane) * 8) = v;
}

// ---------------------------------------------------------------------------
// stage1: P1 = rel @ W1 + b1, P2 = rel @ W2 + b2  (bf16 MFMA, fp32 out)
// 576 blocks: mt = b>>1, which = b&1. 256 threads = 4 waves, wave = 64 cols.
// ---------------------------------------------------------------------------
__global__ __launch_bounds__(256) void stage1_kernel(
    const float* __restrict__ rel,
    const ushort_t* __restrict__ w1F, const ushort_t* __restrict__ w2F,
    const float* __restrict__ b1, const float* __restrict__ b2,
    float* __restrict__ p1, float* __restrict__ p2)
{
    __shared__ __align__(16) char ldsA[16 * RD * 2];   // 16 KB
    int blk = blockIdx.x;
    int mt = blk >> 1, which = blk & 1;
    const ushort_t* wF = which ? w2F : w1F;
    const float* bias  = which ? b2 : b1;
    float* out         = which ? p2 : p1;
    int tid = threadIdx.x, wid = tid >> 6, lane = tid & 63;
    int lr = lane & 15, lg = lane >> 4;

#pragma unroll
    for (int it = 0; it < 8; ++it) {
        int rr = it * 2 + (tid >> 7);
        int c  = (tid & 127) * 4;
        float4 v = *reinterpret_cast<const float4*>(rel + (size_t)(mt * 16 + rr) * RD + c);
        short4 s;
        s.x = f2bf_fast(v.x); s.y = f2bf_fast(v.y);
        s.z = f2bf_fast(v.z); s.w = f2bf_fast(v.w);
        *reinterpret_cast<short4*>(ldsA + rr * (RD * 2) + ((c * 2) ^ ((rr & 7) << 4))) = s;
    }
    __syncthreads();

    int n0 = wid * 64;
    f32x4 acc[4] = {};
#pragma unroll
    for (int ks = 0; ks < 16; ++ks) {
        bf16x8 a = *reinterpret_cast<const bf16x8*>(
            ldsA + lr * (RD * 2) + ((ks * 64 + lg * 16) ^ ((lr & 7) << 4)));
#pragma unroll
        for (int nt = 0; nt < 4; ++nt) {
            int ntG = (n0 >> 4) + nt;
            bf16x8 bfr = *reinterpret_cast<const bf16x8*>(
                wF + ((size_t)(ntG * 16 + ks) * 64 + lane) * 8);
            acc[nt] = __builtin_amdgcn_mfma_f32_16x16x32_bf16(a, bfr, acc[nt], 0, 0, 0);
        }
    }
#pragma unroll
    for (int nt = 0; nt < 4; ++nt) {
        int col = n0 + nt * 16 + lr;
        float bv = bias[col];
#pragma unroll
        for (int r = 0; r < 4; ++r) {
            int orow = mt * 16 + lg * 4 + r;
            out[(size_t)orow * MD + col] = acc[nt][r] + bv;
        }
    }
}

// ---------------------------------------------------------------------------
// stage2 (best measured configuration, = R11/R17): one block per (b,s,o1),
// transposed GEMM h^T = We^T * prod^T. XCD swizzle for group L2 locality.
// Epilogue: LN apply -> ALL THREE 16-row chunks staged in a 48KB LDS buffer
// -> ONE barrier -> one uninterrupted 48KB burst of wave-contiguous 1KB
// stores (the fill-kernel pattern; worth +13us vs scattered stores).
// Staging loads issued before afrag loads (staging feeds the first barrier).
// ---------------------------------------------------------------------------
__global__ __launch_bounds__(512, 4) void stage2_kernel(
    const float* __restrict__ p1, const float* __restrict__ p2,
    const ushort_t* __restrict__ weF,
    const float* __restrict__ be, const float* __restrict__ gamma,
    const float* __restrict__ beta, float* __restrict__ out)
{
    __shared__ __align__(16) char lds[49152];   // prod tile (24.5K) / epilogue (48K)
    __shared__ float pS1[NO][8];
    __shared__ float pS2[NO][8];
    __shared__ float muS[NO];
    __shared__ float rsS[NO];

    int d    = blockIdx.x;
    int bid  = (d & 7) * 576 + (d >> 3);   // 4608 = 8*576, bijective
    int grp  = (bid / NO) * NO;
    int tid  = threadIdx.x;
    int wid  = tid >> 6;
    int lane = tid & 63;
    int lr   = lane & 15;
    int lg   = lane >> 4;
    int m0w  = wid * 32;              // wave's n-row base

    // ---- stage prod rows into LDS (coalesced 1KB reads, swizzled writes) ----
    const float* p1r = p1 + (size_t)bid * MD;
#pragma unroll
    for (int i = 0; i < 6; ++i) {
        int r  = i * 8 + wid;
        int m0 = lane * 4;
        float4 x = *reinterpret_cast<const float4*>(p1r + m0);
        float4 y = *reinterpret_cast<const float4*>(p2 + (size_t)(grp + r) * MD + m0);
        short4 s;
        s.x = f2bf_fast(x.x * y.x); s.y = f2bf_fast(x.y * y.y);
        s.z = f2bf_fast(x.z * y.z); s.w = f2bf_fast(x.w * y.w);
        *reinterpret_cast<short4*>(lds + r * (MD * 2) + ((m0 * 2) ^ ((r & 7) << 4))) = s;
    }

    // ---- A fragments (weF): 16 coalesced 1KB loads (needed after barrier) ----
    bf16x8 afrag[2][8];
#pragma unroll
    for (int mt = 0; mt < 2; ++mt) {
        int ntG = (m0w >> 4) + mt;
#pragma unroll
        for (int ks = 0; ks < 8; ++ks)
            afrag[mt][ks] = *reinterpret_cast<const bf16x8*>(
                weF + ((size_t)(ntG * 8 + ks) * 64 + lane) * 8);
    }
    __syncthreads();

    // ---- K-loop: A from regs, B from LDS ----
    f32x4 acc[2][3] = {};
#pragma unroll
    for (int ks = 0; ks < 8; ++ks) {
        bf16x8 b[3];
#pragma unroll
        for (int nt = 0; nt < 3; ++nt) {
            int r = nt * 16 + lr;
            b[nt] = *reinterpret_cast<const bf16x8*>(
                lds + r * (MD * 2) + ((ks * 64 + lg * 16) ^ ((r & 7) << 4)));
        }
#pragma unroll
        for (int mt = 0; mt < 2; ++mt)
#pragma unroll
            for (int nt = 0; nt < 3; ++nt)
                acc[mt][nt] = __builtin_amdgcn_mfma_f32_16x16x32_bf16(
                    afrag[mt][ks], b[nt], acc[mt][nt], 0, 0, 0);
    }

    // ---- add be (per-n = per output row of h^T) ----
#pragma unroll
    for (int mt = 0; mt < 2; ++mt) {
        float4 bev = *reinterpret_cast<const float4*>(be + m0w + mt * 16 + lg * 4);
#pragma unroll
        for (int nt = 0; nt < 3; ++nt) {
            acc[mt][nt][0] += bev.x; acc[mt][nt][1] += bev.y;
            acc[mt][nt][2] += bev.z; acc[mt][nt][3] += bev.w;
        }
    }

    // ---- LN partials: per col r, lane-local 8-sum + xor16 + xor32 ----
#pragma unroll
    for (int nt = 0; nt < 3; ++nt) {
        float s1 = 0.f, s2 = 0.f;
#pragma unroll
        for (int mt = 0; mt < 2; ++mt)
#pragma unroll
            for (int r = 0; r < 4; ++r) {
                float v = acc[mt][nt][r];
                s1 += v; s2 += v * v;
            }
        s1 += __shfl_xor(s1, 16); s2 += __shfl_xor(s2, 16);
        s1 += __shfl_xor(s1, 32); s2 += __shfl_xor(s2, 32);
        if (lane < 16) {
            pS1[nt * 16 + lane][wid] = s1;
            pS2[nt * 16 + lane][wid] = s2;
        }
    }
    __syncthreads();   // pS ready; also fences last K-loop lds reads

    // ---- finalize stats: one thread per col ----
    if (tid < NO) {
        f32x4 a0 = *reinterpret_cast<const f32x4*>(&pS1[tid][0]);
        f32x4 a1 = *reinterpret_cast<const f32x4*>(&pS1[tid][4]);
        f32x4 b0 = *reinterpret_cast<const f32x4*>(&pS2[tid][0]);
        f32x4 b1v = *reinterpret_cast<const f32x4*>(&pS2[tid][4]);
        float S1 = a0[0]+a0[1]+a0[2]+a0[3] + a1[0]+a1[1]+a1[2]+a1[3];
        float S2 = b0[0]+b0[1]+b0[2]+b0[3] + b1v[0]+b1v[1]+b1v[2]+b1v[3];
        float m  = S1 * (1.0f / MD);
        float var = S2 * (1.0f / MD) - m * m;
        muS[tid] = m;
        rsS[tid] = rsqrtf(var + LN_EPS);
    }
    __syncthreads();

    // ---- epilogue: LN apply -> stage all 3 chunks (48KB) -> ONE barrier ->
    //      one contiguous 48KB store burst (wave-contiguous 1KB per instr).
    float4 g4[2], b4[2];
#pragma unroll
    for (int mt = 0; mt < 2; ++mt) {
        g4[mt] = *reinterpret_cast<const float4*>(gamma + m0w + mt * 16 + lg * 4);
        b4[mt] = *reinterpret_cast<const float4*>(beta  + m0w + mt * 16 + lg * 4);
    }
#pragma unroll
    for (int nt = 0; nt < 3; ++nt) {
        int r = nt * 16 + lr;
        float mu = muS[r];
        float rs = rsS[r];
#pragma unroll
        for (int mt = 0; mt < 2; ++mt) {
            float4 o;
            o.x = (acc[mt][nt][0] - mu) * rs * g4[mt].x + b4[mt].x;
            o.y = (acc[mt][nt][1] - mu) * rs * g4[mt].y + b4[mt].y;
            o.z = (acc[mt][nt][2] - mu) * rs * g4[mt].z + b4[mt].z;
            o.w = (acc[mt][nt][3] - mu) * rs * g4[mt].w + b4[mt].w;
            int n4 = (m0w + mt * 16 + lg * 4) * 4;           // byte offset of n
            *reinterpret_cast<float4*>(
                lds + nt * 16384 + lr * 1024 + (n4 ^ ((lr & 7) << 4))) = o;
        }
    }
    __syncthreads();   // all 48 rows staged

    size_t ob = (size_t)bid * NO * MD;
#pragma unroll
    for (int nt = 0; nt < 3; ++nt) {
#pragma unroll
        for (int j = 0; j < 2; ++j) {
            int rl = wid * 2 + j;     // 16 rows per chunk, 2 per wave
            float4 o = *reinterpret_cast<const float4*>(
                lds + nt * 16384 + rl * 1024 + ((lane * 16) ^ ((rl & 7) << 4)));
            *reinterpret_cast<float4*>(
                out + ob + (size_t)(nt * 16 + rl) * MD + lane * 4) = o;
        }
    }
}

// ---------------------------------------------------------------------------
extern "C" void kernel_launch(void* const* d_in, const int* in_sizes, int n_in,
                              void* d_out, int out_size, void* d_ws, size_t ws_size,
                              hipStream_t stream) {
    const float* rel   = (const float*)d_in[0];
    const float* W1    = (const float*)d_in[1];
    const float* b1    = (const float*)d_in[2];
    const float* W2    = (const float*)d_in[3];
    const float* b2    = (const float*)d_in[4];
    const float* We    = (const float*)d_in[5];
    const float* be    = (const float*)d_in[6];
    const float* gamma = (const float*)d_in[7];
    const float* beta  = (const float*)d_in[8];
    float* out = (float*)d_out;

    char* ws = (char*)d_ws;
    // ws layout (bytes): w1F 512K | w2F 512K | weF 128K | p1 4.5M | p2 4.5M
    ushort_t* w1F = (ushort_t*)(ws);
    ushort_t* w2F = (ushort_t*)(ws + 524288);
    ushort_t* weF = (ushort_t*)(ws + 1048576);
    float*    p1  = (float*)   (ws + 1179648);
    float*    p2  = (float*)   (ws + 1179648 + 4718592);

    prep_kernel<<<80, 512, 0, stream>>>(W1, W2, We, w1F, w2F, weF);
    stage1_kernel<<<576, 256, 0, stream>>>(rel, w1F, w2F, b1, b2, p1, p2);
    stage2_kernel<<<M1, 512, 0, stream>>>(p1, p2, weF, be, gamma, beta, out);
}